// Round 4
// baseline (477.851 us; speedup 1.0000x reference)
//
#include <hip/hip_runtime.h>
#include <hip/hip_bf16.h>
#include <stdint.h>

// LSTM cell: gates = x@Wx^T + bx + h@Wh^T + bh; i,f,g,o; c=f*c_prev+i*g; h=o*tanh(c)
// Fused GEMM M=4096, N=8192(gate-packed), K=4096, bf16 MFMA.
// 256x256 tile, BK=64, 8 waves, 8-phase counted-vmcnt schedule.
// Staging re-derived (round 4): A-halves of tile+2 staged at ph2, B-halves at
// ph3, wait vmcnt(8) at ph3/ph7 -> youngest staged load has 4 phases of cover
// (was 1 phase in round 3 -> per-K-tile latency stall).

#define M_DIM 4096
#define N_PACK 8192
#define K_DIM 4096
#define H_DIM 2048

typedef __attribute__((ext_vector_type(8))) short bf16x8;
typedef __attribute__((ext_vector_type(4))) float f32x4;
typedef __attribute__((ext_vector_type(8))) unsigned short ushortx8;

__device__ __forceinline__ unsigned short f2bf(float f) {
    union { float f; uint32_t u; } v; v.f = f;
    uint32_t u = v.u;
    uint32_t r = (u + 0x7FFFu + ((u >> 16) & 1u)) >> 16;
    return (unsigned short)r;
}

__device__ __forceinline__ float fsigmoid(float x) { return 1.0f / (1.0f + __expf(-x)); }
__device__ __forceinline__ float ftanh(float x) { return 2.0f * fsigmoid(2.0f * x) - 1.0f; }

// ---- pack A = [x | h_prev] -> bf16 [4096][4096] row-major ----
__global__ __launch_bounds__(256) void pack_a(const float* __restrict__ x,
                                              const float* __restrict__ h,
                                              unsigned short* __restrict__ A) {
    int i = blockIdx.x * 256 + threadIdx.x;
    int e = i * 8;
    int row = e >> 12;
    int col = e & 4095;
    const float* src = (col < H_DIM) ? (x + (size_t)row * H_DIM + col)
                                     : (h + (size_t)row * H_DIM + (col - H_DIM));
    float4 f0 = ((const float4*)src)[0];
    float4 f1 = ((const float4*)src)[1];
    ushortx8 o;
    o[0] = f2bf(f0.x); o[1] = f2bf(f0.y); o[2] = f2bf(f0.z); o[3] = f2bf(f0.w);
    o[4] = f2bf(f1.x); o[5] = f2bf(f1.y); o[6] = f2bf(f1.z); o[7] = f2bf(f1.w);
    *(ushortx8*)(A + e) = o;
}

// ---- pack W = gate-interleaved [Wx | Wh] -> bf16 [8192][4096] ----
__global__ __launch_bounds__(256) void pack_w(const float* __restrict__ Wx,
                                              const float* __restrict__ Wh,
                                              unsigned short* __restrict__ W) {
    int i = blockIdx.x * 256 + threadIdx.x;
    int e = i * 8;
    int p = e >> 12;
    int k = e & 4095;
    int g  = (p >> 4) & 3;
    int j  = ((p >> 6) << 4) | (p & 15);
    int orig = g * H_DIM + j;
    const float* src = (k < H_DIM) ? (Wx + (size_t)orig * H_DIM + k)
                                   : (Wh + (size_t)orig * H_DIM + (k - H_DIM));
    float4 f0 = ((const float4*)src)[0];
    float4 f1 = ((const float4*)src)[1];
    ushortx8 o;
    o[0] = f2bf(f0.x); o[1] = f2bf(f0.y); o[2] = f2bf(f0.z); o[3] = f2bf(f0.w);
    o[4] = f2bf(f1.x); o[5] = f2bf(f1.y); o[6] = f2bf(f1.z); o[7] = f2bf(f1.w);
    *(ushortx8*)(W + (size_t)p * K_DIM + k) = o;
}

__device__ __forceinline__ void gload_lds16(const void* g, void* l) {
    __builtin_amdgcn_global_load_lds(
        (const __attribute__((address_space(1))) void*)g,
        (__attribute__((address_space(3))) void*)l, 16, 0, 0);
}

#define BAR() __builtin_amdgcn_s_barrier()
#define LGKM0() asm volatile("s_waitcnt lgkmcnt(0)" ::: "memory")
#define VMCNT8() asm volatile("s_waitcnt vmcnt(8)" ::: "memory")
#define VMCNT0() asm volatile("s_waitcnt vmcnt(0)" ::: "memory")

// ---- fused GEMM + LSTM epilogue, 256x256 tile, 8-phase schedule ----
__global__ __launch_bounds__(512, 2) void lstm_gemm8(
        const unsigned short* __restrict__ A,   // [4096][4096] bf16
        const unsigned short* __restrict__ W,   // [8192][4096] bf16 gate-packed
        const float* __restrict__ bx, const float* __restrict__ bh,
        const float* __restrict__ c_prev, float* __restrict__ out) {
    // lds[buf][mat][32KB]: mat 0 = A-tile 256x64, mat 1 = B-tile 256x64
    __shared__ char lds[2][2][32768];

    const int tid  = threadIdx.x;          // 0..511
    const int wid  = tid >> 6;             // 0..7
    const int lane = tid & 63;
    const int wr   = wid >> 2;             // 0..1  (M half)
    const int wc   = wid & 3;              // 0..3  (N quarter)

    // XCD-aware swizzle (512 blocks, 512%8==0 -> bijective)
    const int swz = (blockIdx.x & 7) * 64 + (blockIdx.x >> 3);
    const int bm  = swz & 15;              // 16 M tiles
    const int bn  = swz >> 4;              // 32 N tiles

    const char* Ab = (const char*)A + (size_t)(bm * 256) * (K_DIM * 2);
    const char* Wb = (const char*)W + (size_t)(bn * 256) * (K_DIM * 2);

    // staging geometry: issue q (0..3) covers rows q*64+srow, 16B swizzled col
    const int srow = tid >> 3;                                   // 0..63
    const int skb  = ((tid & 7) << 4) ^ ((srow & 7) << 4);       // involution

    auto stage_mat = [&](int buf, int mat, int kt) {   // 4 gloads: full 256x64
        const char* gb = mat ? Wb : Ab;
        #pragma unroll
        for (int q = 0; q < 4; ++q) {
            const char* src = gb + (size_t)(q * 64 + srow) * (K_DIM * 2) + kt * 128 + skb;
            gload_lds16(src, &lds[buf][mat][q * 8192 + tid * 16]);
        }
    };

    f32x4 acc[8][4] = {};
    bf16x8 A0[4][2], A1[4][2], Bq[2][2];

    auto read_a = [&](int buf, int qm, bf16x8 (&ar)[4][2]) {
        #pragma unroll
        for (int mf = 0; mf < 4; ++mf) {
            int row = wr * 128 + (qm * 4 + mf) * 16 + (lane & 15);
            #pragma unroll
            for (int kk = 0; kk < 2; ++kk) {
                int cb = (kk * 64 + ((lane >> 4) << 4)) ^ ((row & 7) << 4);
                ar[mf][kk] = *(const bf16x8*)&lds[buf][0][row * 128 + cb];
            }
        }
    };
    auto read_b = [&](int buf, int qn) {
        #pragma unroll
        for (int nf = 0; nf < 2; ++nf) {
            int row = wc * 64 + (qn * 2 + nf) * 16 + (lane & 15);
            #pragma unroll
            for (int kk = 0; kk < 2; ++kk) {
                int cb = (kk * 64 + ((lane >> 4) << 4)) ^ ((row & 7) << 4);
                Bq[nf][kk] = *(const bf16x8*)&lds[buf][1][row * 128 + cb];
            }
        }
    };

#define MMA_Q(QM, QN, AR)                                                      \
    do {                                                                       \
        __builtin_amdgcn_s_setprio(1);                                         \
        _Pragma("unroll")                                                      \
        for (int mf = 0; mf < 4; ++mf) {                                       \
            _Pragma("unroll")                                                  \
            for (int nf = 0; nf < 2; ++nf) {                                   \
                _Pragma("unroll")                                              \
                for (int kk = 0; kk < 2; ++kk) {                               \
                    acc[(QM)*4+mf][(QN)*2+nf] =                                \
                        __builtin_amdgcn_mfma_f32_16x16x32_bf16(               \
                            AR[mf][kk], Bq[nf][kk],                            \
                            acc[(QM)*4+mf][(QN)*2+nf], 0, 0, 0);               \
                }                                                              \
            }                                                                  \
        }                                                                      \
        __builtin_amdgcn_s_setprio(0);                                         \
    } while (0)

    // ---- prologue: T0 -> buf0, T1 -> buf1; wait T0 (T1 stays in flight) ----
    stage_mat(0, 0, 0); stage_mat(0, 1, 0);     // 8 loads (T0)
    stage_mat(1, 0, 1); stage_mat(1, 1, 1);     // 8 loads (T1)
    VMCNT8();                                   // T0 complete; T1 in flight
    BAR();

    // ---- main loop: iteration = K-tiles (2it -> buf0, 2it+1 -> buf1) ----
    for (int it = 0; it < 32; ++it) {
        const int te2  = 2 * it + 2;            // staged into buf0 (ph2/ph3)
        const int to2  = 2 * it + 3;            // staged into buf1 (ph6/ph7)
        const bool last = (it == 31);

        // ph0: read buf0 A0 + B0 (12 ds_reads)
        read_a(0, 0, A0); read_b(0, 0);
        BAR(); LGKM0(); MMA_Q(0, 0, A0); BAR();

        // ph1: read buf0 A1 (8)   [A region of buf0 fully read after this]
        read_a(0, 1, A1);
        BAR(); LGKM0(); MMA_Q(1, 0, A1); BAR();

        // ph2: read buf0 B1 (4); stage buf0 A <- te2 (A region free)
        read_b(0, 1);
        if (!last) stage_mat(0, 0, te2);
        BAR(); LGKM0(); MMA_Q(0, 1, A0); BAR();

        // ph3: stage buf0 B <- te2 (B region free); wait: buf1 (2it+1) complete
        if (!last) { stage_mat(0, 1, te2); VMCNT8(); }
        else       { VMCNT0(); }
        BAR(); MMA_Q(1, 1, A1); BAR();

        // ph4: read buf1 A0 + B0
        read_a(1, 0, A0); read_b(1, 0);
        BAR(); LGKM0(); MMA_Q(0, 0, A0); BAR();

        // ph5: read buf1 A1
        read_a(1, 1, A1);
        BAR(); LGKM0(); MMA_Q(1, 0, A1); BAR();

        // ph6: read buf1 B1; stage buf1 A <- to2
        read_b(1, 1);
        if (!last) stage_mat(1, 0, to2);
        BAR(); LGKM0(); MMA_Q(0, 1, A0); BAR();

        // ph7: stage buf1 B <- to2; wait: buf0 (te2) complete
        if (!last) { stage_mat(1, 1, to2); VMCNT8(); }
        BAR(); MMA_Q(1, 1, A1); BAR();
    }

    // ---- LSTM epilogue (thread-local: n-fragment == gate) ----
    const int jlo  = lane & 15;
    const int rgrp = lane >> 4;
    const int j    = (bn * 4 + wc) * 16 + jlo;     // output column in [0,2048)

    const float bi  = bx[j]             + bh[j];
    const float bff = bx[H_DIM + j]     + bh[H_DIM + j];
    const float bg  = bx[2 * H_DIM + j] + bh[2 * H_DIM + j];
    const float bo  = bx[3 * H_DIM + j] + bh[3 * H_DIM + j];

    float* out_h = out;
    float* out_c = out + (size_t)M_DIM * H_DIM;

    #pragma unroll
    for (int m = 0; m < 8; ++m) {
        int row0 = bm * 256 + wr * 128 + m * 16 + rgrp * 4;
        #pragma unroll
        for (int r = 0; r < 4; ++r) {
            int row = row0 + r;
            float pi = acc[m][0][r] + bi;
            float pf = acc[m][1][r] + bff;
            float pg = acc[m][2][r] + bg;
            float po = acc[m][3][r] + bo;
            float i_ = fsigmoid(pi);
            float f_ = fsigmoid(pf);
            float g_ = ftanh(pg);
            float o_ = fsigmoid(po);
            float cp = c_prev[(size_t)row * H_DIM + j];
            float c  = f_ * cp + i_ * g_;
            float hh = o_ * ftanh(c);
            out_h[(size_t)row * H_DIM + j] = hh;
            out_c[(size_t)row * H_DIM + j] = c;
        }
    }
}

extern "C" void kernel_launch(void* const* d_in, const int* in_sizes, int n_in,
                              void* d_out, int out_size, void* d_ws, size_t ws_size,
                              hipStream_t stream) {
    const float* x      = (const float*)d_in[0];
    const float* h_prev = (const float*)d_in[1];
    const float* c_prev = (const float*)d_in[2];
    const float* Wx     = (const float*)d_in[3];
    const float* bx     = (const float*)d_in[4];
    const float* Wh     = (const float*)d_in[5];
    const float* bh     = (const float*)d_in[6];

    unsigned short* Acat = (unsigned short*)d_ws;                         // 32 MB
    unsigned short* Wp   = (unsigned short*)d_ws + (size_t)M_DIM * K_DIM; // 64 MB

    float* out = (float*)d_out;

    pack_a<<<8192, 256, 0, stream>>>(x, h_prev, Acat);
    pack_w<<<16384, 256, 0, stream>>>(Wx, Wh, Wp);
    // GEMM: (4096/256) * (8192/256) = 16*32 = 512 blocks, 512 threads
    lstm_gemm8<<<512, 512, 0, stream>>>(Acat, Wp, bx, bh, c_prev, out);
}